// Round 3
// baseline (1997.315 us; speedup 1.0000x reference)
//
#include <hip/hip_runtime.h>
#include <hip/hip_bf16.h>
#include <cstdint>

// Problem constants (ViT-Base, 14x14 window + CLS)
#define BATCH 128
#define NTOK  197
#define NHEAD 12

typedef __attribute__((ext_vector_type(8))) __bf16 bf16x8;
typedef __attribute__((ext_vector_type(4))) float f32x4;
typedef __attribute__((ext_vector_type(4))) unsigned short ushort4v;

#define KSTR 72   // LDS row stride (bf16 elems) for attn tiles: uniform banks

__device__ __forceinline__ unsigned short f2bf(float f) {
    union { float f; unsigned int u; } v; v.f = f;
    unsigned int r = (v.u + 0x7FFFu + ((v.u >> 16) & 1u)) >> 16;   // RNE
    return (unsigned short)r;
}

// async global->LDS 16B per lane; LDS dest wave-uniform base + lane*16
__device__ __forceinline__ void async_cp16(const void* gsrc, void* lds_dst) {
    __builtin_amdgcn_global_load_lds(
        (const __attribute__((address_space(1))) unsigned int*)((uintptr_t)gsrc),
        (__attribute__((address_space(3))) unsigned int*)((uintptr_t)lds_dst),
        16, 0, 0);
}

// ---------------------------------------------------------------------------
// K0: bias in MFMA C/D fragment order:
//   BT[h][qt16][kt][quad][l16][j*4+r] = rpb[rel_idx[qn][kn]][h]
// ---------------------------------------------------------------------------
__global__ void bias_tiles(const float* __restrict__ rpb,
                           const int* __restrict__ rel_idx,
                           float* __restrict__ BT) {
    int idx = blockIdx.x * 256 + threadIdx.x;          // exactly 786432
    int r    = idx & 3;
    int j    = (idx >> 2) & 3;
    int l16  = (idx >> 4) & 15;
    int quad = (idx >> 8) & 3;
    int kt   = (idx >> 10) & 3;
    int qt   = (idx >> 12) & 15;
    int h    = idx >> 16;                              // 0..11
    int qn = qt * 16 + quad * 4 + r; if (qn > 196) qn = 196;
    int kn = kt * 64 + j * 16 + l16;
    float v = 0.f;
    if (kn < NTOK) v = rpb[rel_idx[qn * NTOK + kn] * NHEAD + h];
    BT[idx] = v;
}

// ---------------------------------------------------------------------------
// fp32 -> bf16 (RNE), vectorized x4
// ---------------------------------------------------------------------------
__global__ __launch_bounds__(256) void cvt_bf16(const float4* __restrict__ src,
                                                ushort4v* __restrict__ dst, int n4) {
    int i = blockIdx.x * 256 + threadIdx.x;
    if (i >= n4) return;
    float4 f = src[i];
    ushort4v o;
    o.x = f2bf(f.x); o.y = f2bf(f.y); o.z = f2bf(f.z); o.w = f2bf(f.w);
    dst[i] = o;
}

// ---------------------------------------------------------------------------
// bf16 MFMA NT GEMM, 256x256 tile, BK=32, 8 waves (2M x 4N), per-wave 128x64.
// LDS: 2 buffers x (A 256x32 + B 256x32) bf16 = 64 KiB -> 2 blocks/CU.
// Latency hiding = cross-block TLP (m97 mechanism): per K-tile exactly one
// {vmcnt(0); s_barrier}; stage(kt+1) issued right after (1-tile lead), the
// other resident block's MFMAs cover the boundary stall.
// LDS layout (per 256x32 region): two m-rows packed per 128B LDS row,
// chunk slot = c ^ ((row>>1)&3). ds_read_b128 of a 16-row frag then hits
// 8 distinct 16B slots covering all 32 banks -> only 2-way alias (free).
// Staging: global src pre-permuted so linear global_load_lds dest yields
// this layout (lane l: row = 2*(l>>3)+((l>>2)&1), c = (l&3)^((l>>3)&3)).
// EPI=0: +qkv bias, q*=0.125, scatter BF16 q/k/v [Bc,H,N,64]
// EPI=1: +proj bias -> fp32 out [m][768]
// ---------------------------------------------------------------------------
template <int EPI>
__global__ __launch_bounds__(512, 4) void gemm_mfma(
    const unsigned short* __restrict__ A,   // [Mc][768] bf16
    const unsigned short* __restrict__ W,   // [Nn][768] bf16
    const float* __restrict__ bias1, const float* __restrict__ bias2,
    unsigned short* __restrict__ oq, unsigned short* __restrict__ ok,
    unsigned short* __restrict__ ov, float* __restrict__ outf,
    int Mc) {
    __shared__ unsigned short lds[32768];   // 64 KiB

    const int t    = threadIdx.x;
    const int lane = t & 63;
    const int wave = t >> 6;          // 0..7
    const int wm   = wave >> 2;       // 0..1  M half (128 rows)
    const int wn   = wave & 3;        // 0..3  N quarter (64 cols)
    const int quad = lane >> 4;
    const int l16  = lane & 15;

    // ---- T1: bijective XCD-aware block swizzle (m204) ----
    const int gx  = gridDim.x;
    const int nwg = gx * gridDim.y;
    const int orig = blockIdx.y * gx + blockIdx.x;
    const int q8 = nwg >> 3, r8 = nwg & 7;
    const int xcd = orig & 7, rest = orig >> 3;
    const int wg = (xcd < r8 ? xcd * (q8 + 1) : r8 * (q8 + 1) + (xcd - r8) * q8) + rest;
    const int m0 = (wg / gx) * 256;
    const int n0 = (wg % gx) * 256;

    // ---- staging lane geometry (derivation spot-checked lanes 0,3,4,8,11):
    //      instr i covers LDS bytes i*8192+wave*1024+lane*16 of a region;
    //      row = i*128 + wave*16 + 2*(lane>>3) + ((lane>>2)&1),
    //      k-chunk c = (lane&3) ^ ((lane>>3)&3)  (inverse of read swizzle).
    const int grow = wave * 16 + ((lane >> 3) << 1) + ((lane >> 2) & 1);
    const int kcol = (((lane & 3) ^ ((lane >> 3) & 3)) << 3);    // elems
    const unsigned short* Ag[2];
    const unsigned short* Bg[2];
#pragma unroll
    for (int i = 0; i < 2; i++) {
        int ra = m0 + i * 128 + grow; if (ra >= Mc) ra = Mc - 1;
        Ag[i] = A + (size_t)ra * 768 + kcol;
        Bg[i] = W + (size_t)(n0 + i * 128 + grow) * 768 + kcol;
    }

    auto stage = [&](int buf, int kt) {
        unsigned short* base = lds + buf * 16384 + wave * 512;
        async_cp16(Ag[0] + kt * 32, base);
        async_cp16(Ag[1] + kt * 32, base + 4096);
        async_cp16(Bg[0] + kt * 32, base + 8192);
        async_cp16(Bg[1] + kt * 32, base + 12288);
    };

    // ---- fragment read offsets (shorts): row = frag_base + l16,
    //      addr = (row>>1)*64 + (row&1)*32 + ((quad ^ ((row>>1)&3))<<3);
    //      frag_base multiples of 16 keep the XOR term = (l16>>1)&3.
    const int xorc = (l16 >> 1) & 3;
    const int aoff = (wm * 64 + (l16 >> 1)) * 64 + (l16 & 1) * 32 + ((quad ^ xorc) << 3);
    const int boff = 8192 + (wn * 32 + (l16 >> 1)) * 64 + (l16 & 1) * 32 + ((quad ^ xorc) << 3);

    f32x4 acc[8][4] = {};

    stage(0, 0);
#pragma unroll 2
    for (int kt = 0; kt < 24; kt++) {
        const int buf = kt & 1;
        asm volatile("s_waitcnt vmcnt(0)" ::: "memory");   // my 4 loads for kt done
        __builtin_amdgcn_s_barrier();                      // all waves' loads done
        if (kt < 23) stage(buf ^ 1, kt + 1);               // into dead buffer kt-1
        __builtin_amdgcn_sched_barrier(0);                 // keep issue early

        const unsigned short* Lb = lds + buf * 16384;
        bf16x8 af[8], bfr[4];
#pragma unroll
        for (int mf = 0; mf < 8; mf++) af[mf] = *(const bf16x8*)(Lb + aoff + mf * 512);
#pragma unroll
        for (int nf = 0; nf < 4; nf++) bfr[nf] = *(const bf16x8*)(Lb + boff + nf * 512);
        asm volatile("s_waitcnt lgkmcnt(0)" ::: "memory");
        __builtin_amdgcn_sched_barrier(0);                 // rule #18
        __builtin_amdgcn_s_setprio(1);
#pragma unroll
        for (int mf = 0; mf < 8; mf++)
#pragma unroll
            for (int nf = 0; nf < 4; nf++)
                acc[mf][nf] = __builtin_amdgcn_mfma_f32_16x16x32_bf16(
                    af[mf], bfr[nf], acc[mf][nf], 0, 0, 0);
        __builtin_amdgcn_s_setprio(0);
    }

    // ---- epilogue (verified R1/R2): C/D col = l16 (n), row = quad*4+r (m) ----
    if (EPI == 0) {
        const int part   = n0 / 768;
        const float scale = (part == 0) ? 0.125f : 1.f;
        unsigned short* dst = (part == 0) ? oq : (part == 1 ? ok : ov);
        const int nb = (n0 - part * 768) + wn * 64;    // head-aligned within part
        const int h  = nb >> 6;                        // one head per wave
#pragma unroll
        for (int nf = 0; nf < 4; nf++) {
            const int d = nf * 16 + l16;
            const float bb = (part == 0) ? bias1[nb + nf * 16 + l16]
                           : (part == 2 ? bias2[nb + nf * 16 + l16] : 0.f);
#pragma unroll
            for (int mf = 0; mf < 8; mf++) {
                const int mb = m0 + wm * 128 + mf * 16 + quad * 4;
#pragma unroll
                for (int r = 0; r < 4; r++) {
                    const int m = mb + r;
                    if (m < Mc) {
                        const int bi  = m / NTOK;
                        const int tok = m - bi * NTOK;
                        dst[(((size_t)bi * NHEAD + h) * NTOK + tok) * 64 + d] =
                            f2bf((acc[mf][nf][r] + bb) * scale);
                    }
                }
            }
        }
    } else {
#pragma unroll
        for (int nf = 0; nf < 4; nf++) {
            const int col = n0 + wn * 64 + nf * 16 + l16;
            const float bb = bias1[col];
#pragma unroll
            for (int mf = 0; mf < 8; mf++) {
                const int mb = m0 + wm * 128 + mf * 16 + quad * 4;
#pragma unroll
                for (int r = 0; r < 4; r++) {
                    const int m = mb + r;
                    if (m < Mc) outf[(size_t)m * 768 + col] = acc[mf][nf][r] + bb;
                }
            }
        }
    }
}

// ---------------------------------------------------------------------------
// K2: MFMA flash attention. One block per (b,h); 4 waves x 64 q-rows.
//   S = q.k^T (acc initialized with rpb fragments), fixed-max softmax,
//   P -> per-wave LDS (C/D -> A-layout), O += P.V via MFMA. Fp32 l-sum,
//   reduced once at the end. All LDS rows stride KSTR=72 (uniform banks).
// ---------------------------------------------------------------------------
__global__ __launch_bounds__(256, 2) void attn_mfma(
    const unsigned short* __restrict__ Q, const unsigned short* __restrict__ K,
    const unsigned short* __restrict__ V, const float* __restrict__ BT,
    unsigned short* __restrict__ AO) {
    __shared__ unsigned short Ks[64 * KSTR];       // K-tile  [key][d]
    __shared__ unsigned short Vt[64 * KSTR];       // V-tile^T [d][key]
    __shared__ unsigned short Ps[4][64 * KSTR];    // per-wave P [q][key]

    const int t    = threadIdx.x;
    const int lane = t & 63;
    const int wave = t >> 6;
    const int quad = lane >> 4;
    const int l16  = lane & 15;
    const int bh   = blockIdx.x;
    const int b    = bh / NHEAD;
    const int h    = bh - b * NHEAD;

    const unsigned short* qb = Q + (size_t)bh * NTOK * 64;
    const unsigned short* kb = K + (size_t)bh * NTOK * 64;
    const unsigned short* vb = V + (size_t)bh * NTOK * 64;

    // Q fragments in registers for the whole kernel (A-layout: m=l16, k=quad*8+j)
    bf16x8 qf[4][2];
#pragma unroll
    for (int i = 0; i < 4; i++) {
        int tok = wave * 64 + i * 16 + l16; if (tok > 196) tok = 196;
#pragma unroll
        for (int ks = 0; ks < 2; ks++)
            qf[i][ks] = *(const bf16x8*)&qb[(size_t)tok * 64 + ks * 32 + quad * 8];
    }

    f32x4 O[4][4] = {};
    float lsum[4][4] = {};        // [i][r]

    for (int kt = 0; kt < 4; kt++) {
        __syncthreads();          // prior iteration's Ks/Vt reads complete
        {   // stage Ks [key][d], stride 72: thread -> row t>>2, 32B chunk t&3
            const int row = t >> 2, cg = t & 3;
            int gk = kt * 64 + row; if (gk > 196) gk = 196;
            const uint4* src = (const uint4*)&kb[(size_t)gk * 64 + cg * 16];
            *(uint4*)&Ks[row * KSTR + cg * 16]     = src[0];
            *(uint4*)&Ks[row * KSTR + cg * 16 + 8] = src[1];
        }
        {   // stage Vt [d][key] transposed: thread -> key t&63, d-group t>>6
            const int key = t & 63, dg = t >> 6;
            int gk = kt * 64 + key; if (gk > 196) gk = 196;
            union { uint4 v4[2]; unsigned short u[16]; } tmp;
            const uint4* src = (const uint4*)&vb[(size_t)gk * 64 + dg * 16];
            tmp.v4[0] = src[0]; tmp.v4[1] = src[1];
#pragma unroll
            for (int u = 0; u < 16; u++) Vt[(dg * 16 + u) * KSTR + key] = tmp.u[u];
        }
        __syncthreads();

        // ---- acc init = rpb fragments (coalesced dwordx4, L2-hit) ----
        f32x4 acc[4][4];
#pragma unroll
        for (int i = 0; i < 4; i++) {
            const float4* bp = (const float4*)&BT[
                (((((size_t)h * 16 + (wave * 4 + i)) * 4 + kt) * 4 + quad) * 16 + l16) * 16];
#pragma unroll
            for (int j = 0; j < 4; j++) {
                float4 f = bp[j];
                acc[i][j] = (f32x4){f.x, f.y, f.z, f.w};
            }
        }

        // ---- S = q.k^T + bias ----
#pragma unroll
        for (int ks = 0; ks < 2; ks++) {
            bf16x8 kf[4];
#pragma unroll
            for (int j = 0; j < 4; j++)
                kf[j] = *(const bf16x8*)&Ks[(j * 16 + l16) * KSTR + ks * 32 + quad * 8];
#pragma unroll
            for (int i = 0; i < 4; i++)
#pragma unroll
                for (int j = 0; j < 4; j++)
                    acc[i][j] = __builtin_amdgcn_mfma_f32_16x16x32_bf16(
                        qf[i][ks], kf[j], acc[i][j], 0, 0, 0);
        }

        // ---- fixed-max softmax: p = exp(s), masked keys -> 0; write P ----
#pragma unroll
        for (int j = 0; j < 4; j++) {
            const int kn = kt * 64 + j * 16 + l16;
            const bool kval = (kn < NTOK);
#pragma unroll
            for (int i = 0; i < 4; i++)
#pragma unroll
                for (int r = 0; r < 4; r++) {
                    float p = kval ? __expf(fminf(acc[i][j][r], 30.f)) : 0.f;
                    lsum[i][r] += p;
                    Ps[wave][(i * 16 + quad * 4 + r) * KSTR + j * 16 + l16] = f2bf(p);
                }
        }
        // in-wave LDS write->read ordering: compiler inserts lgkmcnt; no barrier
        // needed (Ps[wave] is wave-private).

        // ---- O += P.V ----
#pragma unroll
        for (int ks = 0; ks < 2; ks++) {
            bf16x8 vf[4], pf[4];
#pragma unroll
            for (int jd = 0; jd < 4; jd++)
                vf[jd] = *(const bf16x8*)&Vt[(jd * 16 + l16) * KSTR + ks * 32 + quad * 8];
#pragma unroll
            for (int i = 0; i < 4; i++)
                pf[i] = *(const bf16x8*)&Ps[wave][(i * 16 + l16) * KSTR + ks * 32 + quad * 8];
#pragma unroll
            for (int i = 0; i < 4; i++)
#pragma unroll
                for (int jd = 0; jd < 4; jd++)
                    O[i][jd] = __builtin_amdgcn_mfma_f32_16x16x32_bf16(
                        pf[i], vf[jd], O[i][jd], 0, 0, 0);
        }
    }

    // ---- l-sum reduction across the 16-lane col groups, then store ----
#pragma unroll
    for (int i = 0; i < 4; i++)
#pragma unroll
        for (int r = 0; r < 4; r++) {
            float l = lsum[i][r];
            l += __shfl_xor(l, 1); l += __shfl_xor(l, 2);
            l += __shfl_xor(l, 4); l += __shfl_xor(l, 8);
            lsum[i][r] = 1.f / l;
        }
#pragma unroll
    for (int i = 0; i < 4; i++) {
        const int tb = wave * 64 + i * 16 + quad * 4;
#pragma unroll
        for (int r = 0; r < 4; r++) {
            const int tok = tb + r;
            if (tok < NTOK) {
                const float rl = lsum[i][r];
#pragma unroll
                for (int jd = 0; jd < 4; jd++)
                    AO[((size_t)b * NTOK + tok) * 768 + h * 64 + jd * 16 + l16] =
                        f2bf(O[i][jd][r] * rl);
            }
        }
    }
}

// ---------------------------------------------------------------------------
extern "C" void kernel_launch(void* const* d_in, const int* in_sizes, int n_in,
                              void* d_out, int out_size, void* d_ws, size_t ws_size,
                              hipStream_t stream) {
    const float* x      = (const float*)d_in[0];
    const float* qkv_w  = (const float*)d_in[1];
    const float* q_bias = (const float*)d_in[2];
    const float* v_bias = (const float*)d_in[3];
    const float* rpb    = (const float*)d_in[4];
    const float* proj_w = (const float*)d_in[5];
    const float* proj_b = (const float*)d_in[6];
    const int*   rel_idx = (const int*)d_in[7];
    float* out = (float*)d_out;

    const size_t EB   = 151296;                    // 12*197*64 = 197*768
    const size_t NBT  = 786432;                    // bias tiles (floats)
    const size_t NX   = (size_t)BATCH * NTOK * 768;
    const size_t NWQ  = (size_t)2304 * 768;
    const size_t NWP  = (size_t)768 * 768;

    // layout: BT(f32) | xbf | wqkv | wproj | q,k,v,ao (all bf16)
    const size_t fixed_bytes = NBT * 4 + (NX + NWQ + NWP) * 2;
    int Bc = BATCH;
    while (Bc > 1 && fixed_bytes + 8ull * Bc * EB > ws_size) Bc >>= 1;
    if (fixed_bytes + 8ull * Bc * EB > ws_size) return;
    const int nc = BATCH / Bc;
    const int Mc = Bc * NTOK;
    const int Gy = (Mc + 255) / 256;

    float* BT             = (float*)d_ws;
    unsigned short* xbf   = (unsigned short*)(BT + NBT);
    unsigned short* wqkv  = xbf + NX;
    unsigned short* wproj = wqkv + NWQ;
    unsigned short* q     = wproj + NWP;
    unsigned short* k     = q + (size_t)Bc * EB;
    unsigned short* v     = k + (size_t)Bc * EB;
    unsigned short* aobf  = v + (size_t)Bc * EB;

    bias_tiles<<<(int)(NBT / 256), 256, 0, stream>>>(rpb, rel_idx, BT);
    cvt_bf16<<<(int)((NX / 4 + 255) / 256), 256, 0, stream>>>(
        (const float4*)x, (ushort4v*)xbf, (int)(NX / 4));
    cvt_bf16<<<(int)((NWQ / 4 + 255) / 256), 256, 0, stream>>>(
        (const float4*)qkv_w, (ushort4v*)wqkv, (int)(NWQ / 4));
    cvt_bf16<<<(int)((NWP / 4 + 255) / 256), 256, 0, stream>>>(
        (const float4*)proj_w, (ushort4v*)wproj, (int)(NWP / 4));

    for (int c = 0; c < nc; c++) {
        gemm_mfma<0><<<dim3(2304 / 256, Gy), 512, 0, stream>>>(
            xbf + (size_t)c * Mc * 768, wqkv, q_bias, v_bias, q, k, v, nullptr, Mc);
        attn_mfma<<<Bc * NHEAD, 256, 0, stream>>>(q, k, v, BT, aobf);
        gemm_mfma<1><<<dim3(768 / 256, Gy), 512, 0, stream>>>(
            aobf, wproj, proj_b, nullptr, nullptr, nullptr, nullptr,
            out + (size_t)c * Mc * 768, Mc);
    }
}

// Round 5
// 460.331 us; speedup vs baseline: 4.3389x; 4.3389x over previous
//
#include <hip/hip_runtime.h>
#include <hip/hip_bf16.h>
#include <cstdint>

// Problem constants (ViT-Base, 14x14 window + CLS)
#define BATCH 128
#define NTOK  197
#define NHEAD 12

typedef __attribute__((ext_vector_type(8))) __bf16 bf16x8;
typedef __attribute__((ext_vector_type(4))) float f32x4;
typedef __attribute__((ext_vector_type(4))) unsigned short ushort4v;

#define KSTR 72   // LDS row stride (bf16 elems) for attn P tiles: uniform banks

__device__ __forceinline__ unsigned short f2bf(float f) {
    union { float f; unsigned int u; } v; v.f = f;
    unsigned int r = (v.u + 0x7FFFu + ((v.u >> 16) & 1u)) >> 16;   // RNE
    return (unsigned short)r;
}

// async global->LDS 16B per lane; LDS dest wave-uniform base + lane*16
__device__ __forceinline__ void async_cp16(const void* gsrc, void* lds_dst) {
    __builtin_amdgcn_global_load_lds(
        (const __attribute__((address_space(1))) unsigned int*)((uintptr_t)gsrc),
        (__attribute__((address_space(3))) unsigned int*)((uintptr_t)lds_dst),
        16, 0, 0);
}

// ---------------------------------------------------------------------------
// K0: bias in MFMA C/D fragment order:
//   BT[h][qt16][kt][quad][l16][j*4+r] = rpb[rel_idx[qn][kn]][h]
// ---------------------------------------------------------------------------
__global__ void bias_tiles(const float* __restrict__ rpb,
                           const int* __restrict__ rel_idx,
                           float* __restrict__ BT) {
    int idx = blockIdx.x * 256 + threadIdx.x;          // exactly 786432
    int r    = idx & 3;
    int j    = (idx >> 2) & 3;
    int l16  = (idx >> 4) & 15;
    int quad = (idx >> 8) & 3;
    int kt   = (idx >> 10) & 3;
    int qt   = (idx >> 12) & 15;
    int h    = idx >> 16;                              // 0..11
    int qn = qt * 16 + quad * 4 + r; if (qn > 196) qn = 196;
    int kn = kt * 64 + j * 16 + l16;
    float v = 0.f;
    if (kn < NTOK) v = rpb[rel_idx[qn * NTOK + kn] * NHEAD + h];
    BT[idx] = v;
}

// ---------------------------------------------------------------------------
// fp32 -> bf16 (RNE), vectorized x4
// ---------------------------------------------------------------------------
__global__ __launch_bounds__(256) void cvt_bf16(const float4* __restrict__ src,
                                                ushort4v* __restrict__ dst, int n4) {
    int i = blockIdx.x * 256 + threadIdx.x;
    if (i >= n4) return;
    float4 f = src[i];
    ushort4v o;
    o.x = f2bf(f.x); o.y = f2bf(f.y); o.z = f2bf(f.z); o.w = f2bf(f.w);
    dst[i] = o;
}

// zero helper (vt padding must be 0.0bf16, not uninit bits)
__global__ __launch_bounds__(256) void zero_buf(uint4* __restrict__ p, int n) {
    int i = blockIdx.x * 256 + threadIdx.x;
    if (i < n) p[i] = (uint4){0u, 0u, 0u, 0u};
}

// ---------------------------------------------------------------------------
// bf16 MFMA NT GEMM (m97 structure, R0-verified 190us) + T1 XCD swizzle
// (R2-verified: FETCH -62%) + BK=32 XOR bank swizzle (slot = c ^ (row&3),
// pre-swizzled global source; R1-verified pattern scaled to 4 chunks/row).
// K=768, fp32 accum, 128x128 tile, 4 waves, acc[4][4].
// EPI=0: +qkv bias, q*=0.125 -> q,k scatter [Bc,H,N,64]; v -> TRANSPOSED
//        vt [Bc,H,64,256] (tok padded to 256, pad pre-zeroed).
// EPI=1: +proj bias -> fp32 out [m][768]
// ---------------------------------------------------------------------------
template <int EPI>
__global__ __launch_bounds__(256) void gemm_mfma(
    const unsigned short* __restrict__ A,   // [Mc][768] bf16
    const unsigned short* __restrict__ W,   // [Nn][768] bf16
    const float* __restrict__ bias1, const float* __restrict__ bias2,
    unsigned short* __restrict__ oq, unsigned short* __restrict__ ok,
    unsigned short* __restrict__ ov,        // EPI=0: vt [Bc*H*64][256]
    float* __restrict__ outf,
    int Mc) {
    __shared__ unsigned short As[128 * 32];
    __shared__ unsigned short Bs[128 * 32];

    const int t    = threadIdx.x;
    const int lane = t & 63;
    const int wave = t >> 6;
    const int wm   = wave >> 1;
    const int wn   = wave & 1;
    const int quad = lane >> 4;
    const int l16  = lane & 15;

    // ---- T1: bijective XCD-aware block swizzle (m204) ----
    const int gx  = gridDim.x;
    const int nwg = gx * gridDim.y;
    const int orig = blockIdx.y * gx + blockIdx.x;
    const int q8 = nwg >> 3, r8 = nwg & 7;
    const int xcd = orig & 7, rest = orig >> 3;
    const int wg = (xcd < r8 ? xcd * (q8 + 1) : r8 * (q8 + 1) + (xcd - r8) * q8) + rest;
    const int m0 = (wg / gx) * 128;
    const int n0 = (wg % gx) * 128;

    // staging: lane -> row srow, LDS slot (lane&3); global chunk = slot^(row&3)
    const int srow = lane >> 2;
    const int scol = ((lane & 3) ^ (srow & 3)) * 8;      // elems (16B chunks)
    int ar0 = m0 + wave * 32 + srow;      if (ar0 >= Mc) ar0 = Mc - 1;
    int ar1 = m0 + wave * 32 + 16 + srow; if (ar1 >= Mc) ar1 = Mc - 1;
    const unsigned short* Ag0 = A + (size_t)ar0 * 768 + scol;
    const unsigned short* Ag1 = A + (size_t)ar1 * 768 + scol;
    const unsigned short* Wg0 = W + (size_t)(n0 + wave * 32 + srow) * 768 + scol;
    const unsigned short* Wg1 = Wg0 + (size_t)16 * 768;
    unsigned short* Ad0 = As + (wave * 32) * 32;
    unsigned short* Ad1 = As + (wave * 32 + 16) * 32;
    unsigned short* Bd0 = Bs + (wave * 32) * 32;
    unsigned short* Bd1 = Bs + (wave * 32 + 16) * 32;

    // frag reads: row = base + l16 (base mult of 16 -> row&3 = l16&3),
    // slot = quad ^ (l16&3) -> uniform banks (8 lanes per 4-bank group)
    const unsigned short* Afp = As + (wm * 64 + l16) * 32 + ((quad ^ (l16 & 3)) * 8);
    const unsigned short* Bfp = Bs + (wn * 64 + l16) * 32 + ((quad ^ (l16 & 3)) * 8);

    f32x4 acc[4][4] = {};

    for (int k0 = 0; k0 < 768; k0 += 32) {
        __syncthreads();
        async_cp16(Ag0 + k0, Ad0);
        async_cp16(Ag1 + k0, Ad1);
        async_cp16(Wg0 + k0, Bd0);
        async_cp16(Wg1 + k0, Bd1);
        __syncthreads();
        bf16x8 af[4], bfr[4];
#pragma unroll
        for (int i = 0; i < 4; i++) af[i]  = *(const bf16x8*)(Afp + i * 16 * 32);
#pragma unroll
        for (int j = 0; j < 4; j++) bfr[j] = *(const bf16x8*)(Bfp + j * 16 * 32);
#pragma unroll
        for (int i = 0; i < 4; i++)
#pragma unroll
            for (int j = 0; j < 4; j++)
                acc[i][j] = __builtin_amdgcn_mfma_f32_16x16x32_bf16(
                    af[i], bfr[j], acc[i][j], 0, 0, 0);
    }

    if (EPI == 0) {
        const int part = n0 / 768;
        const int nb0  = n0 - part * 768;
        if (part < 2) {
            const float scale = (part == 0) ? 0.125f : 1.f;
            unsigned short* dst = (part == 0) ? oq : ok;
#pragma unroll
            for (int j = 0; j < 4; j++) {
                const int nnb = nb0 + wn * 64 + j * 16;
                const int h   = nnb >> 6;
                const int d   = (nnb & 63) + l16;
                const float bb = (part == 0) ? bias1[nnb + l16] : 0.f;
#pragma unroll
                for (int i = 0; i < 4; i++) {
                    const int mb = m0 + wm * 64 + i * 16 + quad * 4;
#pragma unroll
                    for (int r = 0; r < 4; r++) {
                        const int m = mb + r;
                        if (m < Mc) {
                            const int bi  = m / NTOK;
                            const int tok = m - bi * NTOK;
                            dst[(((size_t)bi * NHEAD + h) * NTOK + tok) * 64 + d] =
                                f2bf((acc[i][j][r] + bb) * scale);
                        }
                    }
                }
            }
        } else {   // v -> transposed vt[(bi*12+h)*64 + d][256]
#pragma unroll
            for (int j = 0; j < 4; j++) {
                const int nnb = nb0 + wn * 64 + j * 16;
                const int h   = nnb >> 6;
                const int d   = (nnb & 63) + l16;
                const float bb = bias2[nnb + l16];
#pragma unroll
                for (int i = 0; i < 4; i++) {
                    const int mb = m0 + wm * 64 + i * 16 + quad * 4;
#pragma unroll
                    for (int r = 0; r < 4; r++) {
                        const int m = mb + r;
                        if (m < Mc) {
                            const int bi  = m / NTOK;
                            const int tok = m - bi * NTOK;
                            ov[(((size_t)bi * NHEAD + h) * 64 + d) * 256 + tok] =
                                f2bf(acc[i][j][r] + bb);
                        }
                    }
                }
            }
        }
    } else {
#pragma unroll
        for (int j = 0; j < 4; j++) {
            const int col = n0 + wn * 64 + j * 16 + l16;
            const float bb = bias1[col];
#pragma unroll
            for (int i = 0; i < 4; i++) {
                const int mb = m0 + wm * 64 + i * 16 + quad * 4;
#pragma unroll
                for (int r = 0; r < 4; r++) {
                    const int m = mb + r;
                    if (m < Mc) outf[(size_t)m * 768 + col] = acc[i][j][r] + bb;
                }
            }
        }
    }
}

// ---------------------------------------------------------------------------
// K2: MFMA flash attention. One block per (b,h); 4 waves x 64 q-rows.
// K and V^T tiles staged via global_load_lds (4 async/thread) into linear
// [64][64] LDS with XOR bank swizzle (pre-swizzled global source, slot =
// chunk ^ (row&7) -- R1-verified pattern, 0 conflicts). V comes pre-
// transposed from the QKV GEMM (vt[b,h,d,tok256], pad zeroed).
// S = q.k^T (acc init = rpb frags), fixed-max softmax, P -> per-wave LDS
// (KSTR=72), O += P.V via MFMA, l-sum reduced at end.
// ---------------------------------------------------------------------------
__global__ __launch_bounds__(256, 2) void attn_mfma(
    const unsigned short* __restrict__ Q, const unsigned short* __restrict__ K,
    const unsigned short* __restrict__ VT, const float* __restrict__ BT,
    unsigned short* __restrict__ AO) {
    __shared__ unsigned short Ks[64 * 64];         // K-tile  [key][d]   (swz)
    __shared__ unsigned short Vt[64 * 64];         // V-tile^T [d][key]  (swz)
    __shared__ unsigned short Ps[4][64 * KSTR];    // per-wave P [q][key]

    const int t    = threadIdx.x;
    const int lane = t & 63;
    const int wave = t >> 6;
    const int quad = lane >> 4;
    const int l16  = lane & 15;
    const int bh   = blockIdx.x;
    const int b    = bh / NHEAD;
    const int h    = bh - b * NHEAD;

    const unsigned short* qb  = Q  + (size_t)bh * NTOK * 64;
    const unsigned short* kb  = K  + (size_t)bh * NTOK * 64;
    const unsigned short* vtg = VT + (size_t)bh * 64 * 256;

    // Q fragments in registers for the whole kernel (A-layout: m=l16, k=quad*8+j)
    bf16x8 qf[4][2];
#pragma unroll
    for (int i = 0; i < 4; i++) {
        int tok = wave * 64 + i * 16 + l16; if (tok > 196) tok = 196;
#pragma unroll
        for (int ks = 0; ks < 2; ks++)
            qf[i][ks] = *(const bf16x8*)&qb[(size_t)tok * 64 + ks * 32 + quad * 8];
    }

    f32x4 O[4][4] = {};
    float lsum[4][4] = {};        // [i][r]

    for (int kt = 0; kt < 4; kt++) {
        __syncthreads();          // prior iteration's Ks/Vt reads complete
        {   // async stage: rows = wave*8 + (lane>>3) (+32 for 2nd instr);
            // LDS linear [row][slot=lane&7]; global chunk = slot ^ (row&7)
            const int rsub = wave * 8 + (lane >> 3);
            const int chk  = ((lane & 7) ^ (lane >> 3)) * 8;     // elems
            int gk0 = kt * 64 + rsub;      if (gk0 > 196) gk0 = 196;
            int gk1 = kt * 64 + 32 + rsub; if (gk1 > 196) gk1 = 196;
            async_cp16(kb + (size_t)gk0 * 64 + chk, Ks + wave * 512);
            async_cp16(kb + (size_t)gk1 * 64 + chk, Ks + 2048 + wave * 512);
            async_cp16(vtg + (size_t)rsub * 256 + kt * 64 + chk, Vt + wave * 512);
            async_cp16(vtg + (size_t)(32 + rsub) * 256 + kt * 64 + chk,
                       Vt + 2048 + wave * 512);
        }

        // ---- acc init = rpb fragments (issued under the async staging) ----
        f32x4 acc[4][4];
#pragma unroll
        for (int i = 0; i < 4; i++) {
            const float4* bp = (const float4*)&BT[
                (((((size_t)h * 16 + (wave * 4 + i)) * 4 + kt) * 4 + quad) * 16 + l16) * 16];
#pragma unroll
            for (int j = 0; j < 4; j++) {
                float4 f = bp[j];
                acc[i][j] = (f32x4){f.x, f.y, f.z, f.w};
            }
        }

        asm volatile("s_waitcnt vmcnt(0)" ::: "memory");
        __builtin_amdgcn_s_barrier();

        // ---- S = q.k^T + bias ----
#pragma unroll
        for (int ks = 0; ks < 2; ks++) {
            bf16x8 kf[4];
#pragma unroll
            for (int j = 0; j < 4; j++)
                kf[j] = *(const bf16x8*)&Ks[(j * 16 + l16) * 64 +
                                            (((ks * 4 + quad) ^ (l16 & 7)) * 8)];
            __builtin_amdgcn_s_setprio(1);
#pragma unroll
            for (int i = 0; i < 4; i++)
#pragma unroll
                for (int j = 0; j < 4; j++)
                    acc[i][j] = __builtin_amdgcn_mfma_f32_16x16x32_bf16(
                        qf[i][ks], kf[j], acc[i][j], 0, 0, 0);
            __builtin_amdgcn_s_setprio(0);
        }

        // ---- fixed-max softmax: p = exp(s), masked keys -> 0; write P ----
#pragma unroll
        for (int j = 0; j < 4; j++) {
            const int kn = kt * 64 + j * 16 + l16;
            const bool kval = (kn < NTOK);
#pragma unroll
            for (int i = 0; i < 4; i++)
#pragma unroll
                for (int r = 0; r < 4; r++) {
                    float p = kval ? __expf(fminf(acc[i][j][r], 30.f)) : 0.f;
                    lsum[i][r] += p;
                    Ps[wave][(i * 16 + quad * 4 + r) * KSTR + j * 16 + l16] = f2bf(p);
                }
        }
        // in-wave LDS write->read ordering: compiler inserts lgkmcnt; no barrier
        // needed (Ps[wave] is wave-private).

        // ---- O += P.V ----
#pragma unroll
        for (int ks = 0; ks < 2; ks++) {
            bf16x8 vf[4], pf[4];
#pragma unroll
            for (int jd = 0; jd < 4; jd++)
                vf[jd] = *(const bf16x8*)&Vt[(jd * 16 + l16) * 64 +
                                             (((ks * 4 + quad) ^ (l16 & 7)) * 8)];
#pragma unroll
            for (int i = 0; i < 4; i++)
                pf[i] = *(const bf16x8*)&Ps[wave][(i * 16 + l16) * KSTR + ks * 32 + quad * 8];
            __builtin_amdgcn_s_setprio(1);
#pragma unroll
            for (int i = 0; i < 4; i++)
#pragma unroll
                for (int jd = 0; jd < 4; jd++)
                    O[i][jd] = __builtin_amdgcn_mfma_f32_16x16x32_bf16(
                        pf[i], vf[jd], O[i][jd], 0, 0, 0);
            __builtin_amdgcn_s_setprio(0);
        }
    }

    // ---- l-sum reduction across the 16-lane col groups, then store ----
#pragma unroll
    for (int i = 0; i < 4; i++)
#pragma unroll
        for (int r = 0; r < 4; r++) {
            float l = lsum[i][r];
            l += __shfl_xor(l, 1); l += __shfl_xor(l, 2);
            l += __shfl_xor(l, 4); l += __shfl_xor(l, 8);
            lsum[i][r] = 1.f / l;
        }
#pragma unroll
    for (int i = 0; i < 4; i++) {
        const int tb = wave * 64 + i * 16 + quad * 4;
#pragma unroll
        for (int r = 0; r < 4; r++) {
            const int tok = tb + r;
            if (tok < NTOK) {
                const float rl = lsum[i][r];
#pragma unroll
                for (int jd = 0; jd < 4; jd++)
                    AO[((size_t)b * NTOK + tok) * 768 + h * 64 + jd * 16 + l16] =
                        f2bf(O[i][jd][r] * rl);
            }
        }
    }
}

// ---------------------------------------------------------------------------
extern "C" void kernel_launch(void* const* d_in, const int* in_sizes, int n_in,
                              void* d_out, int out_size, void* d_ws, size_t ws_size,
                              hipStream_t stream) {
    const float* x      = (const float*)d_in[0];
    const float* qkv_w  = (const float*)d_in[1];
    const float* q_bias = (const float*)d_in[2];
    const float* v_bias = (const float*)d_in[3];
    const float* rpb    = (const float*)d_in[4];
    const float* proj_w = (const float*)d_in[5];
    const float* proj_b = (const float*)d_in[6];
    const int*   rel_idx = (const int*)d_in[7];
    float* out = (float*)d_out;

    const size_t EB   = 151296;                    // 12*197*64 = 197*768
    const size_t VTE  = 196608;                    // 12*64*256 (vt elems/batch)
    const size_t NBT  = 786432;                    // bias tiles (floats)
    const size_t NX   = (size_t)BATCH * NTOK * 768;
    const size_t NWQ  = (size_t)2304 * 768;
    const size_t NWP  = (size_t)768 * 768;

    // layout: BT(f32) | xbf | wqkv | wproj | q,k (EB) | vt (VTE) | ao (EB)
    const size_t fixed_bytes = NBT * 4 + (NX + NWQ + NWP) * 2;
    const size_t per_b = 2ull * (3 * EB + VTE);    // bytes per batch elem
    int Bc = BATCH;
    while (Bc > 1 && fixed_bytes + (size_t)Bc * per_b > ws_size) Bc >>= 1;
    if (fixed_bytes + (size_t)Bc * per_b > ws_size) return;
    const int nc = BATCH / Bc;
    const int Mc = Bc * NTOK;
    const int Gy = (Mc + 127) / 128;

    float* BT             = (float*)d_ws;
    unsigned short* xbf   = (unsigned short*)(BT + NBT);
    unsigned short* wqkv  = xbf + NX;
    unsigned short* wproj = wqkv + NWQ;
    unsigned short* q     = wproj + NWP;
    unsigned short* k     = q + (size_t)Bc * EB;
    unsigned short* vt    = k + (size_t)Bc * EB;
    unsigned short* aobf  = vt + (size_t)Bc * VTE;

    const int nz = Bc * 24576;                     // vt bytes / 16
    zero_buf<<<(nz + 255) / 256, 256, 0, stream>>>((uint4*)vt, nz);
    bias_tiles<<<(int)(NBT / 256), 256, 0, stream>>>(rpb, rel_idx, BT);
    cvt_bf16<<<(int)((NX / 4 + 255) / 256), 256, 0, stream>>>(
        (const float4*)x, (ushort4v*)xbf, (int)(NX / 4));
    cvt_bf16<<<(int)((NWQ / 4 + 255) / 256), 256, 0, stream>>>(
        (const float4*)qkv_w, (ushort4v*)wqkv, (int)(NWQ / 4));
    cvt_bf16<<<(int)((NWP / 4 + 255) / 256), 256, 0, stream>>>(
        (const float4*)proj_w, (ushort4v*)wproj, (int)(NWP / 4));

    for (int c = 0; c < nc; c++) {
        gemm_mfma<0><<<dim3(2304 / 128, Gy), 256, 0, stream>>>(
            xbf + (size_t)c * Mc * 768, wqkv, q_bias, v_bias, q, k, vt, nullptr, Mc);
        attn_mfma<<<Bc * NHEAD, 256, 0, stream>>>(q, k, vt, BT, aobf);
        gemm_mfma<1><<<dim3(768 / 128, Gy), 256, 0, stream>>>(
            aobf, wproj, proj_b, nullptr, nullptr, nullptr, nullptr,
            out + (size_t)c * Mc * 768, Mc);
    }
}